// Round 6
// baseline (202.757 us; speedup 1.0000x reference)
//
#include <hip/hip_runtime.h>
#include <stdint.h>

namespace {

constexpr int kB = 256;
constexpr int kV = 128000;
constexpr int kSplit = 8;                       // V-chunks per row
constexpr int kBlk = 256;
constexpr int kChunk = kV / kSplit;             // 16000, divisible by 8
constexpr int kElem = 8;                        // elements per lane per iter

struct Part { float val; int idx; };

// ---------------------------------------------------------------------------
// JAX threefry2x32, key = (0, 42); partitionable mode: bits[i] = o0 ^ o1 of
// threefry(x0 = 0, x1 = i). Bit-exact vs reference (absmax = 0, R0-R5).
//
// Codegen history: all source-level ILP forms were re-serialized chain-major
// by the compiler (R2-R4, VGPR 24-32, ~78 us). R5's atomic asm blob (ILP-4
// stage-major) reached ~71 us. Work-based model: per-SIMD issue ~37% vs the
// ~65% practical ceiling (m07 pure-FMA ubench) -> remaining headroom is
// instruction count, not scheduling. This build:
//   - fuses init+round1 (x0==0: round1 is x0=x1; x1=rotl(x1,13)^x1), saving
//     8 insts per 4-chain blob;
//   - moves the gumbel epilogue into a second asm blob (stage-major ILP-4),
//     the last compiler-serialized region. Separate from the threefry blob so
//     the loads' s_waitcnt still lands after ~1100 cyc of threefry cover.
//
// Constants: ks1=42, ks2=0x1BD11BF0. Rotations (13,15,26,6)/(17,29,16,24)
// -> alignbit shifts 19,17,6,26 / 15,3,16,8. Injections (verified R5):
//   (+42,+0x1BD11BF1) (+0x1BD11BF0,+2) (x0+0 omitted,+45) (+42,+0x1BD11BF4)
//   (+0x1BD11BF0,+5).
// ---------------------------------------------------------------------------

// one round, 4 chains, stage-major; S = 32 - rotation (string literal)
#define TFR(S) \
  "v_add_u32 %[x00], %[x00], %[x10]\n\t" \
  "v_add_u32 %[x01], %[x01], %[x11]\n\t" \
  "v_add_u32 %[x02], %[x02], %[x12]\n\t" \
  "v_add_u32 %[x03], %[x03], %[x13]\n\t" \
  "v_alignbit_b32 %[x10], %[x10], %[x10], " S "\n\t" \
  "v_alignbit_b32 %[x11], %[x11], %[x11], " S "\n\t" \
  "v_alignbit_b32 %[x12], %[x12], %[x12], " S "\n\t" \
  "v_alignbit_b32 %[x13], %[x13], %[x13], " S "\n\t" \
  "v_xor_b32 %[x10], %[x10], %[x00]\n\t" \
  "v_xor_b32 %[x11], %[x11], %[x01]\n\t" \
  "v_xor_b32 %[x12], %[x12], %[x02]\n\t" \
  "v_xor_b32 %[x13], %[x13], %[x03]\n\t"

// key injections (literal/inline const in src0; vsrc1 is the VGPR)
#define TFI_A(A) \
  "v_add_u32 %[x00], " A ", %[x00]\n\t" \
  "v_add_u32 %[x01], " A ", %[x01]\n\t" \
  "v_add_u32 %[x02], " A ", %[x02]\n\t" \
  "v_add_u32 %[x03], " A ", %[x03]\n\t"
#define TFI_B(Bc) \
  "v_add_u32 %[x10], " Bc ", %[x10]\n\t" \
  "v_add_u32 %[x11], " Bc ", %[x11]\n\t" \
  "v_add_u32 %[x12], " Bc ", %[x12]\n\t" \
  "v_add_u32 %[x13], " Bc ", %[x13]\n\t"

// bits[0..3] for counters base+0..base+3 (bits = x0 ^ x1 after 20 rounds)
__device__ __forceinline__ void threefry4(uint32_t base, uint32_t* bits) {
  uint32_t x00, x01, x02, x03, x10, x11, x12, x13;
  asm(
      // fused init + round 1: x0 = base + (42+c); x1 = rotl(x0,13) ^ x0
      "v_add_u32 %[x00], 42, %[base]\n\t"
      "v_add_u32 %[x01], 43, %[base]\n\t"
      "v_add_u32 %[x02], 44, %[base]\n\t"
      "v_add_u32 %[x03], 45, %[base]\n\t"
      "v_alignbit_b32 %[x10], %[x00], %[x00], 19\n\t"
      "v_alignbit_b32 %[x11], %[x01], %[x01], 19\n\t"
      "v_alignbit_b32 %[x12], %[x02], %[x02], 19\n\t"
      "v_alignbit_b32 %[x13], %[x03], %[x03], 19\n\t"
      "v_xor_b32 %[x10], %[x10], %[x00]\n\t"
      "v_xor_b32 %[x11], %[x11], %[x01]\n\t"
      "v_xor_b32 %[x12], %[x12], %[x02]\n\t"
      "v_xor_b32 %[x13], %[x13], %[x03]\n\t"
      // rounds 2-4
      TFR("17") TFR("6") TFR("26")
      TFI_A("42") TFI_B("0x1BD11BF1")
      TFR("15") TFR("3") TFR("16") TFR("8")
      TFI_A("0x1BD11BF0") TFI_B("2")
      TFR("19") TFR("17") TFR("6") TFR("26")
      TFI_B("45")                                   // x0 += 0 omitted
      TFR("15") TFR("3") TFR("16") TFR("8")
      TFI_A("42") TFI_B("0x1BD11BF4")
      TFR("19") TFR("17") TFR("6") TFR("26")
      TFI_A("0x1BD11BF0") TFI_B("5")
      // bits = x0 ^ x1
      "v_xor_b32 %[x00], %[x00], %[x10]\n\t"
      "v_xor_b32 %[x01], %[x01], %[x11]\n\t"
      "v_xor_b32 %[x02], %[x02], %[x12]\n\t"
      "v_xor_b32 %[x03], %[x03], %[x13]\n\t"
      : [x00] "=&v"(x00), [x01] "=&v"(x01), [x02] "=&v"(x02),
        [x03] "=&v"(x03), [x10] "=&v"(x10), [x11] "=&v"(x11),
        [x12] "=&v"(x12), [x13] "=&v"(x13)
      : [base] "v"(base));
  bits[0] = x00;
  bits[1] = x01;
  bits[2] = x02;
  bits[3] = x03;
}

#undef TFR
#undef TFI_A
#undef TFI_B

// keys[c] = fma(t, gumbel(bits[c]), la[c]), stage-major ILP-4, bit-identical
// IEEE ops to the verified C++ path:
//   f = bitcast(bits>>9 | 0x3f800000) - 1    (lshr; or; subrev 1.0)
//   u = max(f, FLT_MIN=0x00800000)           (ref's max(tiny,f+tiny) ==)
//   z = log2(u); w = log2(-z)                (v_log_f32, neg as input mod)
//   g = fma(-ln2, w, -ln(ln2)); key = fma(t, g, la)
__device__ __forceinline__ void gumbel4_keys(const uint32_t* bits,
                                             const float* la, float t,
                                             float nl2, float nll2,
                                             float* keys) {
  float k0, k1, k2, k3, s0, s1, s2, s3;
  asm("v_lshrrev_b32 %[s0], 9, %[b0]\n\t"
      "v_lshrrev_b32 %[s1], 9, %[b1]\n\t"
      "v_lshrrev_b32 %[s2], 9, %[b2]\n\t"
      "v_lshrrev_b32 %[s3], 9, %[b3]\n\t"
      "v_or_b32 %[s0], 0x3f800000, %[s0]\n\t"
      "v_or_b32 %[s1], 0x3f800000, %[s1]\n\t"
      "v_or_b32 %[s2], 0x3f800000, %[s2]\n\t"
      "v_or_b32 %[s3], 0x3f800000, %[s3]\n\t"
      "v_subrev_f32 %[s0], 1.0, %[s0]\n\t"
      "v_subrev_f32 %[s1], 1.0, %[s1]\n\t"
      "v_subrev_f32 %[s2], 1.0, %[s2]\n\t"
      "v_subrev_f32 %[s3], 1.0, %[s3]\n\t"
      "v_max_f32 %[s0], 0x00800000, %[s0]\n\t"
      "v_max_f32 %[s1], 0x00800000, %[s1]\n\t"
      "v_max_f32 %[s2], 0x00800000, %[s2]\n\t"
      "v_max_f32 %[s3], 0x00800000, %[s3]\n\t"
      "v_log_f32 %[s0], %[s0]\n\t"
      "v_log_f32 %[s1], %[s1]\n\t"
      "v_log_f32 %[s2], %[s2]\n\t"
      "v_log_f32 %[s3], %[s3]\n\t"
      "v_log_f32 %[s0], -%[s0]\n\t"
      "v_log_f32 %[s1], -%[s1]\n\t"
      "v_log_f32 %[s2], -%[s2]\n\t"
      "v_log_f32 %[s3], -%[s3]\n\t"
      "v_fma_f32 %[s0], %[nl2], %[s0], %[nll2]\n\t"
      "v_fma_f32 %[s1], %[nl2], %[s1], %[nll2]\n\t"
      "v_fma_f32 %[s2], %[nl2], %[s2], %[nll2]\n\t"
      "v_fma_f32 %[s3], %[nl2], %[s3], %[nll2]\n\t"
      "v_fma_f32 %[k0], %[t], %[s0], %[l0]\n\t"
      "v_fma_f32 %[k1], %[t], %[s1], %[l1]\n\t"
      "v_fma_f32 %[k2], %[t], %[s2], %[l2]\n\t"
      "v_fma_f32 %[k3], %[t], %[s3], %[l3]\n\t"
      : [k0] "=&v"(k0), [k1] "=&v"(k1), [k2] "=&v"(k2), [k3] "=&v"(k3),
        [s0] "=&v"(s0), [s1] "=&v"(s1), [s2] "=&v"(s2), [s3] "=&v"(s3)
      : [b0] "v"(bits[0]), [b1] "v"(bits[1]), [b2] "v"(bits[2]),
        [b3] "v"(bits[3]), [l0] "v"(la[0]), [l1] "v"(la[1]),
        [l2] "v"(la[2]), [l3] "v"(la[3]), [t] "v"(t), [nl2] "v"(nl2),
        [nll2] "v"(nll2));
  keys[0] = k0;
  keys[1] = k1;
  keys[2] = k2;
  keys[3] = k3;
}

__global__ __launch_bounds__(kBlk, 2) void sampler_partial(
    const float* __restrict__ logits, const float* __restrict__ temps,
    Part* __restrict__ parts) {
  const int r = blockIdx.x / kSplit;
  const int g = blockIdx.x % kSplit;
  const float t = temps[r];
  const bool greedy = (t == 0.0f);
  const int start = g * kChunk;
  const int end = start + kChunk;
  const float* __restrict__ row = logits + (size_t)r * kV;

  float best = -__builtin_inff();
  int bi = 0;

  if (greedy) {
    // pure argmax of raw logits, first-occurrence tie-break (strict >)
    for (int v = start + (int)threadIdx.x * kElem; v + (kElem - 1) < end;
         v += kBlk * kElem) {
      float4 a = *reinterpret_cast<const float4*>(row + v);
      float4 b = *reinterpret_cast<const float4*>(row + v + 4);
      float la[8] = {a.x, a.y, a.z, a.w, b.x, b.y, b.z, b.w};
#pragma unroll
      for (int j = 0; j < 8; ++j) {
        if (la[j] > best) { best = la[j]; bi = v + j; }
      }
    }
  } else {
    constexpr float kNegLn2 = -0.69314718055994530942f;
    constexpr float kNegLnLn2 = 0.36651292058166432701f;  // -ln(ln 2)
    // argmax(la/t + g) == argmax(la + t*g) for t > 0 (monotonic).
    // Order per iter: loads -> 2 threefry blobs (~560 insts, covers the
    // load latency) -> waitcnt -> 2 gumbel blobs -> update.
#pragma clang loop unroll(disable)
    for (int v = start + (int)threadIdx.x * kElem; v + (kElem - 1) < end;
         v += kBlk * kElem) {
      float4 a = *reinterpret_cast<const float4*>(row + v);
      float4 b = *reinterpret_cast<const float4*>(row + v + 4);

      const uint32_t flat = (uint32_t)(r * kV + v);  // < 2^25
      uint32_t bits[8];
      threefry4(flat, bits);
      threefry4(flat + 4u, bits + 4);

      float la[8] = {a.x, a.y, a.z, a.w, b.x, b.y, b.z, b.w};
      float keys[8];
      gumbel4_keys(bits, la, t, kNegLn2, kNegLnLn2, keys);
      gumbel4_keys(bits + 4, la + 4, t, kNegLn2, kNegLnLn2, keys + 4);

      // ascending j + strict > keeps first occurrence on exact ties
#pragma unroll
      for (int j = 0; j < 8; ++j) {
        if (keys[j] > best) { best = keys[j]; bi = v + j; }
      }
    }
  }

  __shared__ float sv[kBlk];
  __shared__ int si[kBlk];
  sv[threadIdx.x] = best;
  si[threadIdx.x] = bi;
  __syncthreads();
  for (int s = kBlk / 2; s > 0; s >>= 1) {
    if ((int)threadIdx.x < s) {
      float ov = sv[threadIdx.x + s]; int oi = si[threadIdx.x + s];
      float mv = sv[threadIdx.x];     int mi = si[threadIdx.x];
      if (ov > mv || (ov == mv && oi < mi)) {
        sv[threadIdx.x] = ov; si[threadIdx.x] = oi;
      }
    }
    __syncthreads();
  }
  if (threadIdx.x == 0) {
    parts[r * kSplit + g].val = sv[0];
    parts[r * kSplit + g].idx = si[0];
  }
}

__global__ __launch_bounds__(kB) void sampler_final(
    const Part* __restrict__ parts, int* __restrict__ out) {
  const int r = threadIdx.x;
  if (r < kB) {
    float bv = -__builtin_inff();
    int bi = 0;
    for (int g = 0; g < kSplit; ++g) {
      Part p = parts[r * kSplit + g];
      if (p.val > bv || (p.val == bv && p.idx < bi)) { bv = p.val; bi = p.idx; }
    }
    out[r] = bi;
  }
}

}  // namespace

extern "C" void kernel_launch(void* const* d_in, const int* in_sizes, int n_in,
                              void* d_out, int out_size, void* d_ws, size_t ws_size,
                              hipStream_t stream) {
  const float* logits = (const float*)d_in[0];
  const float* temps = (const float*)d_in[1];
  int* out = (int*)d_out;
  Part* parts = (Part*)d_ws;  // kB * kSplit * 8 B = 16 KiB

  sampler_partial<<<dim3(kB * kSplit), dim3(kBlk), 0, stream>>>(logits, temps, parts);
  sampler_final<<<dim3(1), dim3(kB), 0, stream>>>(parts, out);
}